// Round 10
// baseline (422.083 us; speedup 1.0000x reference)
//
#include <hip/hip_runtime.h>
#include <hip/hip_fp16.h>

#define TPB 256
#define CHUNK 1024   // elements per scan block (256 threads x 4)
#define EPB 4096     // edges per partition block
#define CSHIFT 8     // coarse bucket = 256 nodes

// ---------------- two-level exclusive scan (in-place safe) ----------------

__global__ __launch_bounds__(256) void scanA_kernel(const int* __restrict__ cnt,
                                                    int* __restrict__ row_ptr,
                                                    int* __restrict__ chunk_sums, int n) {
    __shared__ int ls[256];
    const int t    = threadIdx.x;
    const int base = blockIdx.x * CHUNK;
    const int idx  = base + t * 4;
    int4 v = make_int4(0, 0, 0, 0);
    if (idx + 3 < n) v = *(const int4*)(cnt + idx);
    else {
        if (idx + 0 < n) v.x = cnt[idx + 0];
        if (idx + 1 < n) v.y = cnt[idx + 1];
        if (idx + 2 < n) v.z = cnt[idx + 2];
        if (idx + 3 < n) v.w = cnt[idx + 3];
    }
    int s0 = v.x, s1 = s0 + v.y, s2 = s1 + v.z, s3 = s2 + v.w;
    ls[t] = s3;
    __syncthreads();
    for (int off = 1; off < 256; off <<= 1) {
        int xv = (t >= off) ? ls[t - off] : 0;
        __syncthreads();
        ls[t] += xv;
        __syncthreads();
    }
    int excl = (t == 0) ? 0 : ls[t - 1];
    if (idx + 0 < n) row_ptr[idx + 0] = excl;
    if (idx + 1 < n) row_ptr[idx + 1] = excl + s0;
    if (idx + 2 < n) row_ptr[idx + 2] = excl + s1;
    if (idx + 3 < n) row_ptr[idx + 3] = excl + s2;
    if (t == 255) chunk_sums[blockIdx.x] = ls[255];
}

__global__ __launch_bounds__(256) void scanB_kernel(int* __restrict__ chunk_sums, int nch) {
    __shared__ int ls[256];
    const int t = threadIdx.x;
    ls[t] = (t < nch) ? chunk_sums[t] : 0;
    __syncthreads();
    for (int off = 1; off < 256; off <<= 1) {
        int xv = (t >= off) ? ls[t - off] : 0;
        __syncthreads();
        ls[t] += xv;
        __syncthreads();
    }
    if (t < nch) chunk_sums[t] = (t == 0) ? 0 : ls[t - 1];  // exclusive
}

__global__ __launch_bounds__(256) void scanC_kernel(int* __restrict__ row_ptr,
                                                    const int* __restrict__ chunk_sums, int n) {
    const int base = blockIdx.x * CHUNK;
    const int off  = chunk_sums[blockIdx.x];
    for (int k = threadIdx.x; k < CHUNK; k += 256) {
        int i = base + k;
        if (i < n) row_ptr[i] += off;
    }
}

// ---------------- CSR build: deterministic counting partition ----------------

__global__ __launch_bounds__(256) void hist_kernel(const int* __restrict__ dst,
                                                   int* __restrict__ hist_g,
                                                   int e, int nbc, int nblk) {
    __shared__ int hs[512];
    const int t = threadIdx.x;
    for (int i = t; i < nbc; i += 256) hs[i] = 0;
    __syncthreads();
    const int e0  = blockIdx.x * EPB;
    const int lim = min(e0 + EPB, e);
    for (int i = e0 + t; i < lim; i += 256)
        atomicAdd(&hs[dst[i] >> CSHIFT], 1);
    __syncthreads();
    for (int b = t; b < nbc; b += 256)
        hist_g[b * nblk + blockIdx.x] = hs[b];
}

__global__ __launch_bounds__(256) void partition_kernel(const int* __restrict__ src,
                                                        const int* __restrict__ dst,
                                                        const int* __restrict__ hist_scan,
                                                        int2* __restrict__ pairs,
                                                        int e, int nbc, int nblk) {
    __shared__ int  hs[512];
    __shared__ int  lscan[512];
    __shared__ int  lfill[512];
    __shared__ int  base_s[512];
    __shared__ int  ls[256];
    __shared__ int2 sp[EPB];   // 32 KB staging
    const int t = threadIdx.x;
    for (int i = t; i < nbc; i += 256) { hs[i] = 0; lfill[i] = 0; }
    __syncthreads();
    const int e0  = blockIdx.x * EPB;
    const int lim = min(e0 + EPB, e);
    for (int i = e0 + t; i < lim; i += 256)
        atomicAdd(&hs[dst[i] >> CSHIFT], 1);
    __syncthreads();
    int v0 = (2 * t     < nbc) ? hs[2 * t]     : 0;
    int v1 = (2 * t + 1 < nbc) ? hs[2 * t + 1] : 0;
    ls[t] = v0 + v1;
    __syncthreads();
    for (int off = 1; off < 256; off <<= 1) {
        int xv = (t >= off) ? ls[t - off] : 0;
        __syncthreads();
        ls[t] += xv;
        __syncthreads();
    }
    int excl = (t == 0) ? 0 : ls[t - 1];
    if (2 * t     < nbc) lscan[2 * t]     = excl;
    if (2 * t + 1 < nbc) lscan[2 * t + 1] = excl + v0;
    for (int b = t; b < nbc; b += 256) base_s[b] = hist_scan[b * nblk + blockIdx.x];
    __syncthreads();
    for (int i = e0 + t; i < lim; i += 256) {
        int d = dst[i];
        int b = d >> CSHIFT;
        int r = atomicAdd(&lfill[b], 1);
        sp[lscan[b] + r] = make_int2(src[i], d);
    }
    __syncthreads();
    const int cnt = lim - e0;
    for (int i = t; i < cnt; i += 256) {
        int2 pr = sp[i];
        int  b  = pr.y >> CSHIFT;
        pairs[base_s[b] + (i - lscan[b])] = pr;
    }
}

// One block per 256-node bucket: per-node count + scan in LDS, then write
// row_ptr, dinv, and place csr_src. No global atomics anywhere.
__global__ __launch_bounds__(256) void bucket_finalize_kernel(const int2* __restrict__ pairs,
                                                              const int* __restrict__ hist_scan,
                                                              int* __restrict__ row_ptr,
                                                              float* __restrict__ dinv,
                                                              int* __restrict__ csr_src,
                                                              int n, int e, int nbc, int nblk) {
    __shared__ int cnt_s[256];
    __shared__ int fill[256];
    __shared__ int ls[256];
    const int b   = blockIdx.x;
    const int nb0 = b << CSHIFT;
    const int t   = threadIdx.x;
    const int r0  = hist_scan[b * nblk];                       // bucket start
    const int r1  = (b + 1 < nbc) ? hist_scan[(b + 1) * nblk] : e;
    cnt_s[t] = 0;
    __syncthreads();
    for (int i = r0 + t; i < r1; i += 256)
        atomicAdd(&cnt_s[pairs[i].y - nb0], 1);
    __syncthreads();
    int c = cnt_s[t];
    ls[t] = c;
    __syncthreads();
    for (int off = 1; off < 256; off <<= 1) {
        int xv = (t >= off) ? ls[t - off] : 0;
        __syncthreads();
        ls[t] += xv;
        __syncthreads();
    }
    int excl = (t == 0) ? 0 : ls[t - 1];
    int node = nb0 + t;
    if (node < n) {
        row_ptr[node] = r0 + excl;
        dinv[node]    = rsqrtf((float)(c + 1));   // +1 self-loop
    }
    fill[t] = r0 + excl;
    __syncthreads();
    for (int i = r0 + t; i < r1; i += 256) {
        int2 pr = pairs[i];
        int  p  = atomicAdd(&fill[pr.y - nb0], 1);
        csr_src[p] = pr.x;
    }
    if (b == 0 && t == 0) row_ptr[n] = e;
}

// ---------------- dense transform: HS(fp16) = dinv[row] * (relu?)(X) @ W ----------------
// W in LDS (64/32 KB -> 2/4 blocks per CU); X read straight from global:
// the CG lanes of a col-group issue the SAME address -> broadcast, block
// working set (RPB x 512 B = 32/64 KB) is L1-resident. Register tile 8x4,
// k-blocked by 4: per k4, 4 conflict-free ds_read_b128 + 8 independent
// global dwordx4 feed 128 FMAs. No per-tile barriers.

template <int M, bool RELU>
__global__ __launch_bounds__(256) void gemm_kernel(const float* __restrict__ X,
                                                   const float* __restrict__ W,
                                                   const float* __restrict__ dinv,
                                                   __half* __restrict__ H, int nrows) {
    constexpr int CG  = M / 4;        // col-groups: 32 (M=128) / 16 (M=64)
    constexpr int RG  = 256 / CG;     // row-groups: 8 / 16
    constexpr int R   = 8;            // rows per thread
    constexpr int RPB = RG * R;       // 64 / 128 rows per block
    __shared__ float Wl[128 * M];     // 64 KB / 32 KB

    for (int i = threadIdx.x; i < 128 * M / 4; i += 256)
        ((float4*)Wl)[i] = ((const float4*)W)[i];

    const int  cg   = threadIdx.x % CG;
    const int  rg   = threadIdx.x / CG;
    const long row0 = (long)blockIdx.x * RPB + (long)rg * R;

    // per-row source pointers (clamped to row 0 for OOB; stores guarded)
    const float4* xp[R];
#pragma unroll
    for (int r = 0; r < R; ++r) {
        long row = row0 + r;
        xp[r] = (const float4*)(X + (row < nrows ? row : 0) * 128);
    }
    __syncthreads();

    float4 acc[R];
#pragma unroll
    for (int r = 0; r < R; ++r) acc[r] = make_float4(0.f, 0.f, 0.f, 0.f);

#pragma unroll 4
    for (int k4 = 0; k4 < 32; ++k4) {
        float4 wv[4];
#pragma unroll
        for (int kk = 0; kk < 4; ++kk)
            wv[kk] = ((const float4*)Wl)[(k4 * 4 + kk) * CG + cg];
#pragma unroll
        for (int r = 0; r < R; ++r) {
            float4 xv = xp[r][k4];
            if (RELU) {
                xv.x = fmaxf(xv.x, 0.f); xv.y = fmaxf(xv.y, 0.f);
                xv.z = fmaxf(xv.z, 0.f); xv.w = fmaxf(xv.w, 0.f);
            }
            acc[r].x += xv.x * wv[0].x; acc[r].y += xv.x * wv[0].y;
            acc[r].z += xv.x * wv[0].z; acc[r].w += xv.x * wv[0].w;
            acc[r].x += xv.y * wv[1].x; acc[r].y += xv.y * wv[1].y;
            acc[r].z += xv.y * wv[1].z; acc[r].w += xv.y * wv[1].w;
            acc[r].x += xv.z * wv[2].x; acc[r].y += xv.z * wv[2].y;
            acc[r].z += xv.z * wv[2].z; acc[r].w += xv.z * wv[2].w;
            acc[r].x += xv.w * wv[3].x; acc[r].y += xv.w * wv[3].y;
            acc[r].z += xv.w * wv[3].z; acc[r].w += xv.w * wv[3].w;
        }
    }

#pragma unroll
    for (int r = 0; r < R; ++r) {
        long row = row0 + r;
        if (row < nrows) {
            float dv = dinv[row];
            __half2 p0 = __floats2half2_rn(acc[r].x * dv, acc[r].y * dv);
            __half2 p1 = __floats2half2_rn(acc[r].z * dv, acc[r].w * dv);
            uint2 pk;
            pk.x = *reinterpret_cast<unsigned int*>(&p0);
            pk.y = *reinterpret_cast<unsigned int*>(&p1);
            ((uint2*)(H + row * M))[cg] = pk;
        }
    }
}

// ---------------- pull aggregation: out[d] = b + dinv[d]*(hs[d] + sum hs[src]) ----------------
// R7/R8-proven loop structure; hs is fp16.

template <int M>
__global__ __launch_bounds__(TPB) void agg_pull_kernel(const __half* __restrict__ hs,
                                                       const int* __restrict__ csr_src,
                                                       const int* __restrict__ row_ptr,
                                                       const float* __restrict__ dinv,
                                                       const float* __restrict__ bias,
                                                       float* __restrict__ out, int n) {
    const int node = blockIdx.x * (TPB / 64) + (threadIdx.x >> 6);
    const int lane = threadIdx.x & 63;
    if (node >= n) return;
    const int beg = row_ptr[node];
    const int end = row_ptr[node + 1];

    if constexpr (M == 128) {
        const __half2* hp = (const __half2*)hs;
        float2 a[8];
#pragma unroll
        for (int r = 1; r < 8; ++r) a[r] = make_float2(0.f, 0.f);
        a[0] = __half22float2(hp[(long)node * 64 + lane]);  // self-loop term
        for (int base = beg; base < end; base += 64) {
            int m = end - base; if (m > 64) m = 64;
            int idx = (lane < m) ? csr_src[base + lane] : 0;
            int j = 0;
            for (; j + 8 <= m; j += 8) {
#pragma unroll
                for (int r = 0; r < 8; ++r) {
                    int s = __shfl(idx, j + r);
                    float2 v = __half22float2(hp[(long)s * 64 + lane]);
                    a[r].x += v.x; a[r].y += v.y;
                }
            }
            for (; j < m; ++j) {
                int s = __shfl(idx, j);
                float2 v = __half22float2(hp[(long)s * 64 + lane]);
                a[0].x += v.x; a[0].y += v.y;
            }
        }
#pragma unroll
        for (int r = 4; r < 8; ++r) { a[r - 4].x += a[r].x; a[r - 4].y += a[r].y; }
        float  di = dinv[node];
        float2 bv = ((const float2*)bias)[lane];
        float2 o;
        o.x = bv.x + di * ((a[0].x + a[1].x) + (a[2].x + a[3].x));
        o.y = bv.y + di * ((a[0].y + a[1].y) + (a[2].y + a[3].y));
        ((float2*)out)[(long)node * 64 + lane] = o;
    } else {  // M == 64
        float a[8];
#pragma unroll
        for (int r = 1; r < 8; ++r) a[r] = 0.f;
        a[0] = __half2float(hs[(long)node * 64 + lane]);  // self-loop term
        for (int base = beg; base < end; base += 64) {
            int m = end - base; if (m > 64) m = 64;
            int idx = (lane < m) ? csr_src[base + lane] : 0;
            int j = 0;
            for (; j + 8 <= m; j += 8) {
#pragma unroll
                for (int r = 0; r < 8; ++r) {
                    int s = __shfl(idx, j + r);
                    a[r] += __half2float(hs[(long)s * 64 + lane]);
                }
            }
            for (; j < m; ++j) {
                int s = __shfl(idx, j);
                a[0] += __half2float(hs[(long)s * 64 + lane]);
            }
        }
#pragma unroll
        for (int r = 4; r < 8; ++r) a[r - 4] += a[r];
        float di = dinv[node];
        out[(long)node * 64 + lane] =
            bias[lane] + di * ((a[0] + a[1]) + (a[2] + a[3]));
    }
}

// ---------------- launcher ----------------

extern "C" void kernel_launch(void* const* d_in, const int* in_sizes, int n_in,
                              void* d_out, int out_size, void* d_ws, size_t ws_size,
                              hipStream_t stream) {
    const float* x  = (const float*)d_in[0];
    const int*   ei = (const int*)d_in[1];   // int32 on the wire
    const float* W1 = (const float*)d_in[2];
    const float* b1 = (const float*)d_in[3];
    const float* W2 = (const float*)d_in[4];
    const float* b2 = (const float*)d_in[5];
    float* out = (float*)d_out;

    const int N = in_sizes[0] / 128;   // 100000
    const int E = in_sizes[1] / 2;     // 1600000
    const int* srcv = ei;
    const int* dstv = ei + E;

    const int NBC    = (N + 255) >> CSHIFT;           // 391 coarse buckets
    const int NBLK_E = (E + EPB - 1) / EPB;           // 391 edge blocks
    const int HLEN   = NBC * NBLK_E;                  // 152,881
    const int NCHH   = (HLEN + CHUNK - 1) / CHUNK;    // 150

    // workspace layout
    char* p = (char*)d_ws;
    int*    row_ptr    = (int*)p;           p += ((size_t)N + 64) * 4;
    int*    chunk_sums = (int*)p;           p += 1024;
    int*    hist       = (int*)p;           p += ((size_t)HLEN + 64) * 4;
    int*    csr_src    = (int*)p;           p += (size_t)E * 4;
    float*  dinv       = (float*)p;         p += ((size_t)N + 64) * 4;
    __half* hs1        = (__half*)p;        p += (size_t)N * 128 * 2;
    float*  out1       = (float*)p;         p += (size_t)N * 128 * 4;
    int2*   pairs      = (int2*)out1;       // alias: out1 dead until after CSR build
    __half* hs2        = hs1;               // hs1 dead once out1 complete

    // ---- CSR build + normalization (histogram -> scan -> partition -> finalize) ----
    hist_kernel<<<NBLK_E, 256, 0, stream>>>(dstv, hist, E, NBC, NBLK_E);
    scanA_kernel<<<NCHH, 256, 0, stream>>>(hist, hist, chunk_sums, HLEN);  // in-place safe
    scanB_kernel<<<1, 256, 0, stream>>>(chunk_sums, NCHH);
    scanC_kernel<<<NCHH, 256, 0, stream>>>(hist, chunk_sums, HLEN);
    partition_kernel<<<NBLK_E, 256, 0, stream>>>(srcv, dstv, hist, pairs, E, NBC, NBLK_E);
    bucket_finalize_kernel<<<NBC, 256, 0, stream>>>(pairs, hist, row_ptr, dinv, csr_src,
                                                    N, E, NBC, NBLK_E);

    // ---- layer 1: W-in-LDS, X-from-global, 8x4 register tile ----
    gemm_kernel<128, false><<<(N + 63) / 64, 256, 0, stream>>>(x, W1, dinv, hs1, N);
    agg_pull_kernel<128><<<(N + 3) / 4, TPB, 0, stream>>>(hs1, csr_src, row_ptr, dinv, b1, out1, N);

    // ---- layer 2 ----
    gemm_kernel<64, true><<<(N + 127) / 128, 256, 0, stream>>>(out1, W2, dinv, hs2, N);
    agg_pull_kernel<64><<<(N + 3) / 4, TPB, 0, stream>>>(hs2, csr_src, row_ptr, dinv, b2, out, N);
}

// Round 11
// 316.443 us; speedup vs baseline: 1.3338x; 1.3338x over previous
//
#include <hip/hip_runtime.h>
#include <hip/hip_fp16.h>

#define TPB 256
#define CHUNK 1024   // elements per scan block (256 threads x 4)
#define EPB 4096     // edges per partition block
#define CSHIFT 8     // coarse bucket = 256 nodes

typedef _Float16 half8 __attribute__((ext_vector_type(8)));
typedef float    f32x4 __attribute__((ext_vector_type(4)));

// ---------------- two-level exclusive scan (in-place safe) ----------------

__global__ __launch_bounds__(256) void scanA_kernel(const int* __restrict__ cnt,
                                                    int* __restrict__ row_ptr,
                                                    int* __restrict__ chunk_sums, int n) {
    __shared__ int ls[256];
    const int t    = threadIdx.x;
    const int base = blockIdx.x * CHUNK;
    const int idx  = base + t * 4;
    int4 v = make_int4(0, 0, 0, 0);
    if (idx + 3 < n) v = *(const int4*)(cnt + idx);
    else {
        if (idx + 0 < n) v.x = cnt[idx + 0];
        if (idx + 1 < n) v.y = cnt[idx + 1];
        if (idx + 2 < n) v.z = cnt[idx + 2];
        if (idx + 3 < n) v.w = cnt[idx + 3];
    }
    int s0 = v.x, s1 = s0 + v.y, s2 = s1 + v.z, s3 = s2 + v.w;
    ls[t] = s3;
    __syncthreads();
    for (int off = 1; off < 256; off <<= 1) {
        int xv = (t >= off) ? ls[t - off] : 0;
        __syncthreads();
        ls[t] += xv;
        __syncthreads();
    }
    int excl = (t == 0) ? 0 : ls[t - 1];
    if (idx + 0 < n) row_ptr[idx + 0] = excl;
    if (idx + 1 < n) row_ptr[idx + 1] = excl + s0;
    if (idx + 2 < n) row_ptr[idx + 2] = excl + s1;
    if (idx + 3 < n) row_ptr[idx + 3] = excl + s2;
    if (t == 255) chunk_sums[blockIdx.x] = ls[255];
}

__global__ __launch_bounds__(256) void scanB_kernel(int* __restrict__ chunk_sums, int nch) {
    __shared__ int ls[256];
    const int t = threadIdx.x;
    ls[t] = (t < nch) ? chunk_sums[t] : 0;
    __syncthreads();
    for (int off = 1; off < 256; off <<= 1) {
        int xv = (t >= off) ? ls[t - off] : 0;
        __syncthreads();
        ls[t] += xv;
        __syncthreads();
    }
    if (t < nch) chunk_sums[t] = (t == 0) ? 0 : ls[t - 1];  // exclusive
}

__global__ __launch_bounds__(256) void scanC_kernel(int* __restrict__ row_ptr,
                                                    const int* __restrict__ chunk_sums, int n) {
    const int base = blockIdx.x * CHUNK;
    const int off  = chunk_sums[blockIdx.x];
    for (int k = threadIdx.x; k < CHUNK; k += 256) {
        int i = base + k;
        if (i < n) row_ptr[i] += off;
    }
}

// ---------------- CSR build: deterministic counting partition ----------------

__global__ __launch_bounds__(256) void hist_kernel(const int* __restrict__ dst,
                                                   int* __restrict__ hist_g,
                                                   int e, int nbc, int nblk) {
    __shared__ int hs[512];
    const int t = threadIdx.x;
    for (int i = t; i < nbc; i += 256) hs[i] = 0;
    __syncthreads();
    const int e0  = blockIdx.x * EPB;
    const int lim = min(e0 + EPB, e);
    for (int i = e0 + t; i < lim; i += 256)
        atomicAdd(&hs[dst[i] >> CSHIFT], 1);
    __syncthreads();
    for (int b = t; b < nbc; b += 256)
        hist_g[b * nblk + blockIdx.x] = hs[b];
}

__global__ __launch_bounds__(256) void partition_kernel(const int* __restrict__ src,
                                                        const int* __restrict__ dst,
                                                        const int* __restrict__ hist_scan,
                                                        int2* __restrict__ pairs,
                                                        int e, int nbc, int nblk) {
    __shared__ int  hs[512];
    __shared__ int  lscan[512];
    __shared__ int  lfill[512];
    __shared__ int  base_s[512];
    __shared__ int  ls[256];
    __shared__ int2 sp[EPB];   // 32 KB staging
    const int t = threadIdx.x;
    for (int i = t; i < nbc; i += 256) { hs[i] = 0; lfill[i] = 0; }
    __syncthreads();
    const int e0  = blockIdx.x * EPB;
    const int lim = min(e0 + EPB, e);
    for (int i = e0 + t; i < lim; i += 256)
        atomicAdd(&hs[dst[i] >> CSHIFT], 1);
    __syncthreads();
    int v0 = (2 * t     < nbc) ? hs[2 * t]     : 0;
    int v1 = (2 * t + 1 < nbc) ? hs[2 * t + 1] : 0;
    ls[t] = v0 + v1;
    __syncthreads();
    for (int off = 1; off < 256; off <<= 1) {
        int xv = (t >= off) ? ls[t - off] : 0;
        __syncthreads();
        ls[t] += xv;
        __syncthreads();
    }
    int excl = (t == 0) ? 0 : ls[t - 1];
    if (2 * t     < nbc) lscan[2 * t]     = excl;
    if (2 * t + 1 < nbc) lscan[2 * t + 1] = excl + v0;
    for (int b = t; b < nbc; b += 256) base_s[b] = hist_scan[b * nblk + blockIdx.x];
    __syncthreads();
    for (int i = e0 + t; i < lim; i += 256) {
        int d = dst[i];
        int b = d >> CSHIFT;
        int r = atomicAdd(&lfill[b], 1);
        sp[lscan[b] + r] = make_int2(src[i], d);
    }
    __syncthreads();
    const int cnt = lim - e0;
    for (int i = t; i < cnt; i += 256) {
        int2 pr = sp[i];
        int  b  = pr.y >> CSHIFT;
        pairs[base_s[b] + (i - lscan[b])] = pr;
    }
}

// One block per 256-node bucket: per-node count + scan in LDS, then write
// row_ptr, dinv, and place csr_src. No global atomics anywhere.
__global__ __launch_bounds__(256) void bucket_finalize_kernel(const int2* __restrict__ pairs,
                                                              const int* __restrict__ hist_scan,
                                                              int* __restrict__ row_ptr,
                                                              float* __restrict__ dinv,
                                                              int* __restrict__ csr_src,
                                                              int n, int e, int nbc, int nblk) {
    __shared__ int cnt_s[256];
    __shared__ int fill[256];
    __shared__ int ls[256];
    const int b   = blockIdx.x;
    const int nb0 = b << CSHIFT;
    const int t   = threadIdx.x;
    const int r0  = hist_scan[b * nblk];                       // bucket start
    const int r1  = (b + 1 < nbc) ? hist_scan[(b + 1) * nblk] : e;
    cnt_s[t] = 0;
    __syncthreads();
    for (int i = r0 + t; i < r1; i += 256)
        atomicAdd(&cnt_s[pairs[i].y - nb0], 1);
    __syncthreads();
    int c = cnt_s[t];
    ls[t] = c;
    __syncthreads();
    for (int off = 1; off < 256; off <<= 1) {
        int xv = (t >= off) ? ls[t - off] : 0;
        __syncthreads();
        ls[t] += xv;
        __syncthreads();
    }
    int excl = (t == 0) ? 0 : ls[t - 1];
    int node = nb0 + t;
    if (node < n) {
        row_ptr[node] = r0 + excl;
        dinv[node]    = rsqrtf((float)(c + 1));   // +1 self-loop
    }
    fill[t] = r0 + excl;
    __syncthreads();
    for (int i = r0 + t; i < r1; i += 256) {
        int2 pr = pairs[i];
        int  p  = atomicAdd(&fill[pr.y - nb0], 1);
        csr_src[p] = pr.x;
    }
    if (b == 0 && t == 0) row_ptr[n] = e;
}

// ---------------- dense transform via MFMA: HS(fp16) = dinv[row] * (relu?)(X) @ W ----------------
// fp16 inputs, fp32 accumulate (v_mfma_f32_16x16x32_f16). W is converted once
// per block into LDS in B-fragment order: frag(c,i) at ((c*4+i)*64+lane)*8
// halves -> one conflict-free ds_read_b128 per (c,i) per lane.
// Verified layouts (learn_hip m89/m120): A[m=lane&15][k=quad*8+j];
// C/D: col=lane&15, row=quad*4+reg. Block = 64 rows (4 waves x 16), K=128.

template <int M, bool RELU>
__global__ __launch_bounds__(256) void gemm_mfma_kernel(const float* __restrict__ X,
                                                        const float* __restrict__ W,
                                                        const float* __restrict__ dinv,
                                                        __half* __restrict__ H, int nrows) {
    constexpr int NC = M / 16;                 // col-tiles: 8 (M=128) / 4 (M=64)
    __shared__ __align__(16) _Float16 Wf[NC * 4 * 64 * 8];   // 32 KB / 16 KB

    const int tid = threadIdx.x;

    // ---- stage W into fragment order (fp32 -> fp16) ----
    for (int f = tid; f < NC * 4 * 64; f += 256) {
        int c    = f >> 8;          // f / 256
        int i    = (f >> 6) & 3;
        int lane = f & 63;
        int quad = lane >> 4, n = lane & 15;
        const float* wp = W + (size_t)(i * 32 + quad * 8) * M + c * 16 + n;
        half8 hv;
#pragma unroll
        for (int j = 0; j < 8; ++j) hv[j] = (_Float16)wp[(size_t)j * M];
        ((half8*)Wf)[f] = hv;
    }
    __syncthreads();

    const int  wave = tid >> 6, lane = tid & 63;
    const int  quad = lane >> 4, n16 = lane & 15;
    const long rowbase = (long)blockIdx.x * 64 + wave * 16;

    // ---- A fragments: this lane supplies row (rowbase+n16), k = i*32+quad*8..+7 ----
    long arow = rowbase + n16;
    const float4* xr = (const float4*)(X + (arow < nrows ? arow : 0) * 128);
    half8 a[4];
#pragma unroll
    for (int i = 0; i < 4; ++i) {
        float4 x0 = xr[i * 8 + quad * 2];
        float4 x1 = xr[i * 8 + quad * 2 + 1];
        if (RELU) {
            x0.x = fmaxf(x0.x, 0.f); x0.y = fmaxf(x0.y, 0.f);
            x0.z = fmaxf(x0.z, 0.f); x0.w = fmaxf(x0.w, 0.f);
            x1.x = fmaxf(x1.x, 0.f); x1.y = fmaxf(x1.y, 0.f);
            x1.z = fmaxf(x1.z, 0.f); x1.w = fmaxf(x1.w, 0.f);
        }
        half8 hv;
        hv[0] = (_Float16)x0.x; hv[1] = (_Float16)x0.y;
        hv[2] = (_Float16)x0.z; hv[3] = (_Float16)x0.w;
        hv[4] = (_Float16)x1.x; hv[5] = (_Float16)x1.y;
        hv[6] = (_Float16)x1.z; hv[7] = (_Float16)x1.w;
        a[i] = hv;
    }

    // per-output-row dinv (rows rowbase + quad*4 + r)
    float dv[4];
#pragma unroll
    for (int r = 0; r < 4; ++r) {
        long orow = rowbase + quad * 4 + r;
        dv[r] = (orow < nrows) ? dinv[orow] : 0.f;
    }

    // ---- col-tiles: 4 MFMAs each, epilogue scales + stores fp16 ----
    for (int c = 0; c < NC; ++c) {
        f32x4 acc = {0.f, 0.f, 0.f, 0.f};
#pragma unroll
        for (int i = 0; i < 4; ++i) {
            half8 b = ((const half8*)Wf)[(c * 4 + i) * 64 + lane];
            acc = __builtin_amdgcn_mfma_f32_16x16x32_f16(a[i], b, acc, 0, 0, 0);
        }
#pragma unroll
        for (int r = 0; r < 4; ++r) {
            long orow = rowbase + quad * 4 + r;
            if (orow < nrows)
                H[orow * M + c * 16 + n16] = __float2half(acc[r] * dv[r]);
        }
    }
}

// ---------------- pull aggregation: out[d] = b + dinv[d]*(hs[d] + sum hs[src]) ----------------
// R7/R8-proven loop structure; hs is fp16.

template <int M>
__global__ __launch_bounds__(TPB) void agg_pull_kernel(const __half* __restrict__ hs,
                                                       const int* __restrict__ csr_src,
                                                       const int* __restrict__ row_ptr,
                                                       const float* __restrict__ dinv,
                                                       const float* __restrict__ bias,
                                                       float* __restrict__ out, int n) {
    const int node = blockIdx.x * (TPB / 64) + (threadIdx.x >> 6);
    const int lane = threadIdx.x & 63;
    if (node >= n) return;
    const int beg = row_ptr[node];
    const int end = row_ptr[node + 1];

    if constexpr (M == 128) {
        const __half2* hp = (const __half2*)hs;
        float2 a[8];
#pragma unroll
        for (int r = 1; r < 8; ++r) a[r] = make_float2(0.f, 0.f);
        a[0] = __half22float2(hp[(long)node * 64 + lane]);  // self-loop term
        for (int base = beg; base < end; base += 64) {
            int m = end - base; if (m > 64) m = 64;
            int idx = (lane < m) ? csr_src[base + lane] : 0;
            int j = 0;
            for (; j + 8 <= m; j += 8) {
#pragma unroll
                for (int r = 0; r < 8; ++r) {
                    int s = __shfl(idx, j + r);
                    float2 v = __half22float2(hp[(long)s * 64 + lane]);
                    a[r].x += v.x; a[r].y += v.y;
                }
            }
            for (; j < m; ++j) {
                int s = __shfl(idx, j);
                float2 v = __half22float2(hp[(long)s * 64 + lane]);
                a[0].x += v.x; a[0].y += v.y;
            }
        }
#pragma unroll
        for (int r = 4; r < 8; ++r) { a[r - 4].x += a[r].x; a[r - 4].y += a[r].y; }
        float  di = dinv[node];
        float2 bv = ((const float2*)bias)[lane];
        float2 o;
        o.x = bv.x + di * ((a[0].x + a[1].x) + (a[2].x + a[3].x));
        o.y = bv.y + di * ((a[0].y + a[1].y) + (a[2].y + a[3].y));
        ((float2*)out)[(long)node * 64 + lane] = o;
    } else {  // M == 64
        float a[8];
#pragma unroll
        for (int r = 1; r < 8; ++r) a[r] = 0.f;
        a[0] = __half2float(hs[(long)node * 64 + lane]);  // self-loop term
        for (int base = beg; base < end; base += 64) {
            int m = end - base; if (m > 64) m = 64;
            int idx = (lane < m) ? csr_src[base + lane] : 0;
            int j = 0;
            for (; j + 8 <= m; j += 8) {
#pragma unroll
                for (int r = 0; r < 8; ++r) {
                    int s = __shfl(idx, j + r);
                    a[r] += __half2float(hs[(long)s * 64 + lane]);
                }
            }
            for (; j < m; ++j) {
                int s = __shfl(idx, j);
                a[0] += __half2float(hs[(long)s * 64 + lane]);
            }
        }
#pragma unroll
        for (int r = 4; r < 8; ++r) a[r - 4] += a[r];
        float di = dinv[node];
        out[(long)node * 64 + lane] =
            bias[lane] + di * ((a[0] + a[1]) + (a[2] + a[3]));
    }
}

// ---------------- launcher ----------------

extern "C" void kernel_launch(void* const* d_in, const int* in_sizes, int n_in,
                              void* d_out, int out_size, void* d_ws, size_t ws_size,
                              hipStream_t stream) {
    const float* x  = (const float*)d_in[0];
    const int*   ei = (const int*)d_in[1];   // int32 on the wire
    const float* W1 = (const float*)d_in[2];
    const float* b1 = (const float*)d_in[3];
    const float* W2 = (const float*)d_in[4];
    const float* b2 = (const float*)d_in[5];
    float* out = (float*)d_out;

    const int N = in_sizes[0] / 128;   // 100000
    const int E = in_sizes[1] / 2;     // 1600000
    const int* srcv = ei;
    const int* dstv = ei + E;

    const int NBC    = (N + 255) >> CSHIFT;           // 391 coarse buckets
    const int NBLK_E = (E + EPB - 1) / EPB;           // 391 edge blocks
    const int HLEN   = NBC * NBLK_E;                  // 152,881
    const int NCHH   = (HLEN + CHUNK - 1) / CHUNK;    // 150

    // workspace layout
    char* p = (char*)d_ws;
    int*    row_ptr    = (int*)p;           p += ((size_t)N + 64) * 4;
    int*    chunk_sums = (int*)p;           p += 1024;
    int*    hist       = (int*)p;           p += ((size_t)HLEN + 64) * 4;
    int*    csr_src    = (int*)p;           p += (size_t)E * 4;
    float*  dinv       = (float*)p;         p += ((size_t)N + 64) * 4;
    __half* hs1        = (__half*)p;        p += (size_t)N * 128 * 2;
    float*  out1       = (float*)p;         p += (size_t)N * 128 * 4;
    int2*   pairs      = (int2*)out1;       // alias: out1 dead until after CSR build
    __half* hs2        = hs1;               // hs1 dead once out1 complete

    // ---- CSR build + normalization (histogram -> scan -> partition -> finalize) ----
    hist_kernel<<<NBLK_E, 256, 0, stream>>>(dstv, hist, E, NBC, NBLK_E);
    scanA_kernel<<<NCHH, 256, 0, stream>>>(hist, hist, chunk_sums, HLEN);  // in-place safe
    scanB_kernel<<<1, 256, 0, stream>>>(chunk_sums, NCHH);
    scanC_kernel<<<NCHH, 256, 0, stream>>>(hist, chunk_sums, HLEN);
    partition_kernel<<<NBLK_E, 256, 0, stream>>>(srcv, dstv, hist, pairs, E, NBC, NBLK_E);
    bucket_finalize_kernel<<<NBC, 256, 0, stream>>>(pairs, hist, row_ptr, dinv, csr_src,
                                                    N, E, NBC, NBLK_E);

    // ---- layer 1: MFMA GEMM (fp16 in, fp32 acc) ----
    gemm_mfma_kernel<128, false><<<(N + 63) / 64, 256, 0, stream>>>(x, W1, dinv, hs1, N);
    agg_pull_kernel<128><<<(N + 3) / 4, TPB, 0, stream>>>(hs1, csr_src, row_ptr, dinv, b1, out1, N);

    // ---- layer 2 ----
    gemm_mfma_kernel<64, true><<<(N + 63) / 64, 256, 0, stream>>>(out1, W2, dinv, hs2, N);
    agg_pull_kernel<64><<<(N + 3) / 4, TPB, 0, stream>>>(hs2, csr_src, row_ptr, dinv, b2, out, N);
}

// Round 12
// 312.322 us; speedup vs baseline: 1.3514x; 1.0132x over previous
//
#include <hip/hip_runtime.h>
#include <hip/hip_fp16.h>

#define TPB 256
#define CHUNK 1024   // elements per scan block (256 threads x 4)
#define EPB 4096     // edges per partition block
#define CSHIFT 8     // coarse bucket = 256 nodes

typedef _Float16 half8 __attribute__((ext_vector_type(8)));
typedef float    f32x4 __attribute__((ext_vector_type(4)));

// ---------------- two-level exclusive scan (in-place safe) ----------------

__global__ __launch_bounds__(256) void scanA_kernel(const int* __restrict__ cnt,
                                                    int* __restrict__ row_ptr,
                                                    int* __restrict__ chunk_sums, int n) {
    __shared__ int ls[256];
    const int t    = threadIdx.x;
    const int base = blockIdx.x * CHUNK;
    const int idx  = base + t * 4;
    int4 v = make_int4(0, 0, 0, 0);
    if (idx + 3 < n) v = *(const int4*)(cnt + idx);
    else {
        if (idx + 0 < n) v.x = cnt[idx + 0];
        if (idx + 1 < n) v.y = cnt[idx + 1];
        if (idx + 2 < n) v.z = cnt[idx + 2];
        if (idx + 3 < n) v.w = cnt[idx + 3];
    }
    int s0 = v.x, s1 = s0 + v.y, s2 = s1 + v.z, s3 = s2 + v.w;
    ls[t] = s3;
    __syncthreads();
    for (int off = 1; off < 256; off <<= 1) {
        int xv = (t >= off) ? ls[t - off] : 0;
        __syncthreads();
        ls[t] += xv;
        __syncthreads();
    }
    int excl = (t == 0) ? 0 : ls[t - 1];
    if (idx + 0 < n) row_ptr[idx + 0] = excl;
    if (idx + 1 < n) row_ptr[idx + 1] = excl + s0;
    if (idx + 2 < n) row_ptr[idx + 2] = excl + s1;
    if (idx + 3 < n) row_ptr[idx + 3] = excl + s2;
    if (t == 255) chunk_sums[blockIdx.x] = ls[255];
}

__global__ __launch_bounds__(256) void scanB_kernel(int* __restrict__ chunk_sums, int nch) {
    __shared__ int ls[256];
    const int t = threadIdx.x;
    ls[t] = (t < nch) ? chunk_sums[t] : 0;
    __syncthreads();
    for (int off = 1; off < 256; off <<= 1) {
        int xv = (t >= off) ? ls[t - off] : 0;
        __syncthreads();
        ls[t] += xv;
        __syncthreads();
    }
    if (t < nch) chunk_sums[t] = (t == 0) ? 0 : ls[t - 1];  // exclusive
}

__global__ __launch_bounds__(256) void scanC_kernel(int* __restrict__ row_ptr,
                                                    const int* __restrict__ chunk_sums, int n) {
    const int base = blockIdx.x * CHUNK;
    const int off  = chunk_sums[blockIdx.x];
    for (int k = threadIdx.x; k < CHUNK; k += 256) {
        int i = base + k;
        if (i < n) row_ptr[i] += off;
    }
}

// ---------------- CSR build: deterministic counting partition ----------------

__global__ __launch_bounds__(256) void hist_kernel(const int* __restrict__ dst,
                                                   int* __restrict__ hist_g,
                                                   int e, int nbc, int nblk) {
    __shared__ int hs[512];
    const int t = threadIdx.x;
    for (int i = t; i < nbc; i += 256) hs[i] = 0;
    __syncthreads();
    const int e0  = blockIdx.x * EPB;
    const int lim = min(e0 + EPB, e);
    for (int i = e0 + t; i < lim; i += 256)
        atomicAdd(&hs[dst[i] >> CSHIFT], 1);
    __syncthreads();
    for (int b = t; b < nbc; b += 256)
        hist_g[b * nblk + blockIdx.x] = hs[b];
}

// pairs entries are PACKED 32-bit: (dst_local << 17) | src   (N=100000 < 2^17)
__global__ __launch_bounds__(256) void partition_kernel(const int* __restrict__ src,
                                                        const int* __restrict__ dst,
                                                        const int* __restrict__ hist_scan,
                                                        int* __restrict__ pairs,
                                                        int e, int nbc, int nblk) {
    __shared__ int  hs[512];
    __shared__ int  lscan[512];
    __shared__ int  lfill[512];
    __shared__ int  base_s[512];
    __shared__ int  ls[256];
    __shared__ int2 sp[EPB];   // 32 KB staging
    const int t = threadIdx.x;
    for (int i = t; i < nbc; i += 256) { hs[i] = 0; lfill[i] = 0; }
    __syncthreads();
    const int e0  = blockIdx.x * EPB;
    const int lim = min(e0 + EPB, e);
    for (int i = e0 + t; i < lim; i += 256)
        atomicAdd(&hs[dst[i] >> CSHIFT], 1);
    __syncthreads();
    int v0 = (2 * t     < nbc) ? hs[2 * t]     : 0;
    int v1 = (2 * t + 1 < nbc) ? hs[2 * t + 1] : 0;
    ls[t] = v0 + v1;
    __syncthreads();
    for (int off = 1; off < 256; off <<= 1) {
        int xv = (t >= off) ? ls[t - off] : 0;
        __syncthreads();
        ls[t] += xv;
        __syncthreads();
    }
    int excl = (t == 0) ? 0 : ls[t - 1];
    if (2 * t     < nbc) lscan[2 * t]     = excl;
    if (2 * t + 1 < nbc) lscan[2 * t + 1] = excl + v0;
    for (int b = t; b < nbc; b += 256) base_s[b] = hist_scan[b * nblk + blockIdx.x];
    __syncthreads();
    for (int i = e0 + t; i < lim; i += 256) {
        int d = dst[i];
        int b = d >> CSHIFT;
        int r = atomicAdd(&lfill[b], 1);
        sp[lscan[b] + r] = make_int2(src[i], d);
    }
    __syncthreads();
    const int cnt = lim - e0;
    for (int i = t; i < cnt; i += 256) {
        int2 pr = sp[i];
        int  b  = pr.y >> CSHIFT;
        pairs[base_s[b] + (i - lscan[b])] = pr.x | ((pr.y & 255) << 17);
    }
}

// One block per 256-node bucket: per-node count + scan in LDS, then write
// row_ptr, dinv, and place csr_src. No global atomics anywhere.
__global__ __launch_bounds__(256) void bucket_finalize_kernel(const int* __restrict__ pairs,
                                                              const int* __restrict__ hist_scan,
                                                              int* __restrict__ row_ptr,
                                                              float* __restrict__ dinv,
                                                              int* __restrict__ csr_src,
                                                              int n, int e, int nbc, int nblk) {
    __shared__ int cnt_s[256];
    __shared__ int fill[256];
    __shared__ int ls[256];
    const int b   = blockIdx.x;
    const int nb0 = b << CSHIFT;
    const int t   = threadIdx.x;
    const int r0  = hist_scan[b * nblk];                       // bucket start
    const int r1  = (b + 1 < nbc) ? hist_scan[(b + 1) * nblk] : e;
    cnt_s[t] = 0;
    __syncthreads();
    for (int i = r0 + t; i < r1; i += 256)
        atomicAdd(&cnt_s[pairs[i] >> 17], 1);
    __syncthreads();
    int c = cnt_s[t];
    ls[t] = c;
    __syncthreads();
    for (int off = 1; off < 256; off <<= 1) {
        int xv = (t >= off) ? ls[t - off] : 0;
        __syncthreads();
        ls[t] += xv;
        __syncthreads();
    }
    int excl = (t == 0) ? 0 : ls[t - 1];
    int node = nb0 + t;
    if (node < n) {
        row_ptr[node] = r0 + excl;
        dinv[node]    = rsqrtf((float)(c + 1));   // +1 self-loop
    }
    fill[t] = r0 + excl;
    __syncthreads();
    for (int i = r0 + t; i < r1; i += 256) {
        int pr = pairs[i];
        int p  = atomicAdd(&fill[pr >> 17], 1);
        csr_src[p] = pr & 0x1FFFF;
    }
    if (b == 0 && t == 0) row_ptr[n] = e;
}

// ---------------- dense transform via MFMA: HS(fp16) = dinv[row] * (relu?)(X) @ W ----------------
// R11-proven. A[m=lane&15][k=quad*8+j]; C/D: col=lane&15, row=quad*4+reg.

template <int M, bool RELU>
__global__ __launch_bounds__(256) void gemm_mfma_kernel(const float* __restrict__ X,
                                                        const float* __restrict__ W,
                                                        const float* __restrict__ dinv,
                                                        __half* __restrict__ H, int nrows) {
    constexpr int NC = M / 16;                 // col-tiles: 8 (M=128) / 4 (M=64)
    __shared__ __align__(16) _Float16 Wf[NC * 4 * 64 * 8];   // 32 KB / 16 KB

    const int tid = threadIdx.x;

    for (int f = tid; f < NC * 4 * 64; f += 256) {
        int c    = f >> 8;
        int i    = (f >> 6) & 3;
        int lane = f & 63;
        int quad = lane >> 4, n = lane & 15;
        const float* wp = W + (size_t)(i * 32 + quad * 8) * M + c * 16 + n;
        half8 hv;
#pragma unroll
        for (int j = 0; j < 8; ++j) hv[j] = (_Float16)wp[(size_t)j * M];
        ((half8*)Wf)[f] = hv;
    }
    __syncthreads();

    const int  wave = tid >> 6, lane = tid & 63;
    const int  quad = lane >> 4, n16 = lane & 15;
    const long rowbase = (long)blockIdx.x * 64 + wave * 16;

    long arow = rowbase + n16;
    const float4* xr = (const float4*)(X + (arow < nrows ? arow : 0) * 128);
    half8 a[4];
#pragma unroll
    for (int i = 0; i < 4; ++i) {
        float4 x0 = xr[i * 8 + quad * 2];
        float4 x1 = xr[i * 8 + quad * 2 + 1];
        if (RELU) {
            x0.x = fmaxf(x0.x, 0.f); x0.y = fmaxf(x0.y, 0.f);
            x0.z = fmaxf(x0.z, 0.f); x0.w = fmaxf(x0.w, 0.f);
            x1.x = fmaxf(x1.x, 0.f); x1.y = fmaxf(x1.y, 0.f);
            x1.z = fmaxf(x1.z, 0.f); x1.w = fmaxf(x1.w, 0.f);
        }
        half8 hv;
        hv[0] = (_Float16)x0.x; hv[1] = (_Float16)x0.y;
        hv[2] = (_Float16)x0.z; hv[3] = (_Float16)x0.w;
        hv[4] = (_Float16)x1.x; hv[5] = (_Float16)x1.y;
        hv[6] = (_Float16)x1.z; hv[7] = (_Float16)x1.w;
        a[i] = hv;
    }

    float dv[4];
#pragma unroll
    for (int r = 0; r < 4; ++r) {
        long orow = rowbase + quad * 4 + r;
        dv[r] = (orow < nrows) ? dinv[orow] : 0.f;
    }

    for (int c = 0; c < NC; ++c) {
        f32x4 acc = {0.f, 0.f, 0.f, 0.f};
#pragma unroll
        for (int i = 0; i < 4; ++i) {
            half8 b = ((const half8*)Wf)[(c * 4 + i) * 64 + lane];
            acc = __builtin_amdgcn_mfma_f32_16x16x32_f16(a[i], b, acc, 0, 0, 0);
        }
#pragma unroll
        for (int r = 0; r < 4; ++r) {
            long orow = rowbase + quad * 4 + r;
            if (orow < nrows)
                H[orow * M + c * 16 + n16] = __float2half(acc[r] * dv[r]);
        }
    }
}

// ---------------- pull aggregation: out[d] = b + dinv[d]*(hs[d] + sum hs[src]) ----------------
// 16/4/1 cascade of independent gathers (16 accumulators) for deep MLP.

template <int M>
__global__ __launch_bounds__(TPB) void agg_pull_kernel(const __half* __restrict__ hs,
                                                       const int* __restrict__ csr_src,
                                                       const int* __restrict__ row_ptr,
                                                       const float* __restrict__ dinv,
                                                       const float* __restrict__ bias,
                                                       float* __restrict__ out, int n) {
    const int node = blockIdx.x * (TPB / 64) + (threadIdx.x >> 6);
    const int lane = threadIdx.x & 63;
    if (node >= n) return;
    const int beg = row_ptr[node];
    const int end = row_ptr[node + 1];

    if constexpr (M == 128) {
        const __half2* hp = (const __half2*)hs;
        float2 a[16];
#pragma unroll
        for (int r = 1; r < 16; ++r) a[r] = make_float2(0.f, 0.f);
        a[0] = __half22float2(hp[(long)node * 64 + lane]);  // self-loop term
        for (int base = beg; base < end; base += 64) {
            int m = end - base; if (m > 64) m = 64;
            int idx = (lane < m) ? csr_src[base + lane] : 0;
            int j = 0;
            for (; j + 16 <= m; j += 16) {
#pragma unroll
                for (int r = 0; r < 16; ++r) {
                    int s = __shfl(idx, j + r);
                    float2 v = __half22float2(hp[(long)s * 64 + lane]);
                    a[r].x += v.x; a[r].y += v.y;
                }
            }
            for (; j + 4 <= m; j += 4) {
#pragma unroll
                for (int r = 0; r < 4; ++r) {
                    int s = __shfl(idx, j + r);
                    float2 v = __half22float2(hp[(long)s * 64 + lane]);
                    a[r].x += v.x; a[r].y += v.y;
                }
            }
            for (; j < m; ++j) {
                int s = __shfl(idx, j);
                float2 v = __half22float2(hp[(long)s * 64 + lane]);
                a[0].x += v.x; a[0].y += v.y;
            }
        }
#pragma unroll
        for (int r = 8; r < 16; ++r) { a[r - 8].x += a[r].x; a[r - 8].y += a[r].y; }
#pragma unroll
        for (int r = 4; r < 8; ++r) { a[r - 4].x += a[r].x; a[r - 4].y += a[r].y; }
        float  di = dinv[node];
        float2 bv = ((const float2*)bias)[lane];
        float2 o;
        o.x = bv.x + di * ((a[0].x + a[1].x) + (a[2].x + a[3].x));
        o.y = bv.y + di * ((a[0].y + a[1].y) + (a[2].y + a[3].y));
        ((float2*)out)[(long)node * 64 + lane] = o;
    } else {  // M == 64
        float a[16];
#pragma unroll
        for (int r = 1; r < 16; ++r) a[r] = 0.f;
        a[0] = __half2float(hs[(long)node * 64 + lane]);  // self-loop term
        for (int base = beg; base < end; base += 64) {
            int m = end - base; if (m > 64) m = 64;
            int idx = (lane < m) ? csr_src[base + lane] : 0;
            int j = 0;
            for (; j + 16 <= m; j += 16) {
#pragma unroll
                for (int r = 0; r < 16; ++r) {
                    int s = __shfl(idx, j + r);
                    a[r] += __half2float(hs[(long)s * 64 + lane]);
                }
            }
            for (; j + 4 <= m; j += 4) {
#pragma unroll
                for (int r = 0; r < 4; ++r) {
                    int s = __shfl(idx, j + r);
                    a[r] += __half2float(hs[(long)s * 64 + lane]);
                }
            }
            for (; j < m; ++j) {
                int s = __shfl(idx, j);
                a[0] += __half2float(hs[(long)s * 64 + lane]);
            }
        }
#pragma unroll
        for (int r = 8; r < 16; ++r) a[r - 8] += a[r];
#pragma unroll
        for (int r = 4; r < 8; ++r) a[r - 4] += a[r];
        float di = dinv[node];
        out[(long)node * 64 + lane] =
            bias[lane] + di * ((a[0] + a[1]) + (a[2] + a[3]));
    }
}

// ---------------- launcher ----------------

extern "C" void kernel_launch(void* const* d_in, const int* in_sizes, int n_in,
                              void* d_out, int out_size, void* d_ws, size_t ws_size,
                              hipStream_t stream) {
    const float* x  = (const float*)d_in[0];
    const int*   ei = (const int*)d_in[1];   // int32 on the wire
    const float* W1 = (const float*)d_in[2];
    const float* b1 = (const float*)d_in[3];
    const float* W2 = (const float*)d_in[4];
    const float* b2 = (const float*)d_in[5];
    float* out = (float*)d_out;

    const int N = in_sizes[0] / 128;   // 100000
    const int E = in_sizes[1] / 2;     // 1600000
    const int* srcv = ei;
    const int* dstv = ei + E;

    const int NBC    = (N + 255) >> CSHIFT;           // 391 coarse buckets
    const int NBLK_E = (E + EPB - 1) / EPB;           // 391 edge blocks
    const int HLEN   = NBC * NBLK_E;                  // 152,881
    const int NCHH   = (HLEN + CHUNK - 1) / CHUNK;    // 150

    // workspace layout
    char* p = (char*)d_ws;
    int*    row_ptr    = (int*)p;           p += ((size_t)N + 64) * 4;
    int*    chunk_sums = (int*)p;           p += 1024;
    int*    hist       = (int*)p;           p += ((size_t)HLEN + 64) * 4;
    int*    csr_src    = (int*)p;           p += (size_t)E * 4;
    float*  dinv       = (float*)p;         p += ((size_t)N + 64) * 4;
    __half* hs1        = (__half*)p;        p += (size_t)N * 128 * 2;
    float*  out1       = (float*)p;         p += (size_t)N * 128 * 4;
    int*    pairs      = (int*)out1;        // alias: out1 dead until after CSR build
    __half* hs2        = hs1;               // hs1 dead once out1 complete

    // ---- CSR build + normalization (histogram -> scan -> partition -> finalize) ----
    hist_kernel<<<NBLK_E, 256, 0, stream>>>(dstv, hist, E, NBC, NBLK_E);
    scanA_kernel<<<NCHH, 256, 0, stream>>>(hist, hist, chunk_sums, HLEN);  // in-place safe
    scanB_kernel<<<1, 256, 0, stream>>>(chunk_sums, NCHH);
    scanC_kernel<<<NCHH, 256, 0, stream>>>(hist, chunk_sums, HLEN);
    partition_kernel<<<NBLK_E, 256, 0, stream>>>(srcv, dstv, hist, pairs, E, NBC, NBLK_E);
    bucket_finalize_kernel<<<NBC, 256, 0, stream>>>(pairs, hist, row_ptr, dinv, csr_src,
                                                    N, E, NBC, NBLK_E);

    // ---- layer 1: MFMA GEMM (fp16 in, fp32 acc) ----
    gemm_mfma_kernel<128, false><<<(N + 63) / 64, 256, 0, stream>>>(x, W1, dinv, hs1, N);
    agg_pull_kernel<128><<<(N + 3) / 4, TPB, 0, stream>>>(hs1, csr_src, row_ptr, dinv, b1, out1, N);

    // ---- layer 2 ----
    gemm_mfma_kernel<64, true><<<(N + 63) / 64, 256, 0, stream>>>(out1, W2, dinv, hs2, N);
    agg_pull_kernel<64><<<(N + 3) / 4, TPB, 0, stream>>>(hs2, csr_src, row_ptr, dinv, b2, out, N);
}

// Round 13
// 308.267 us; speedup vs baseline: 1.3692x; 1.0132x over previous
//
#include <hip/hip_runtime.h>
#include <hip/hip_fp16.h>

#define TPB 256
#define CHUNK 1024   // elements per scan block (256 threads x 4)
#define EPB 4096     // edges per partition block
#define CSHIFT 8     // coarse bucket = 256 nodes

typedef _Float16 half8 __attribute__((ext_vector_type(8)));
typedef float    f32x4 __attribute__((ext_vector_type(4)));

// ---------------- two-level exclusive scan (in-place safe) ----------------

__global__ __launch_bounds__(256) void scanA_kernel(const int* __restrict__ cnt,
                                                    int* __restrict__ row_ptr,
                                                    int* __restrict__ chunk_sums, int n) {
    __shared__ int ls[256];
    const int t    = threadIdx.x;
    const int base = blockIdx.x * CHUNK;
    const int idx  = base + t * 4;
    int4 v = make_int4(0, 0, 0, 0);
    if (idx + 3 < n) v = *(const int4*)(cnt + idx);
    else {
        if (idx + 0 < n) v.x = cnt[idx + 0];
        if (idx + 1 < n) v.y = cnt[idx + 1];
        if (idx + 2 < n) v.z = cnt[idx + 2];
        if (idx + 3 < n) v.w = cnt[idx + 3];
    }
    int s0 = v.x, s1 = s0 + v.y, s2 = s1 + v.z, s3 = s2 + v.w;
    ls[t] = s3;
    __syncthreads();
    for (int off = 1; off < 256; off <<= 1) {
        int xv = (t >= off) ? ls[t - off] : 0;
        __syncthreads();
        ls[t] += xv;
        __syncthreads();
    }
    int excl = (t == 0) ? 0 : ls[t - 1];
    if (idx + 0 < n) row_ptr[idx + 0] = excl;
    if (idx + 1 < n) row_ptr[idx + 1] = excl + s0;
    if (idx + 2 < n) row_ptr[idx + 2] = excl + s1;
    if (idx + 3 < n) row_ptr[idx + 3] = excl + s2;
    if (t == 255) chunk_sums[blockIdx.x] = ls[255];
}

__global__ __launch_bounds__(256) void scanB_kernel(int* __restrict__ chunk_sums, int nch) {
    __shared__ int ls[256];
    const int t = threadIdx.x;
    ls[t] = (t < nch) ? chunk_sums[t] : 0;
    __syncthreads();
    for (int off = 1; off < 256; off <<= 1) {
        int xv = (t >= off) ? ls[t - off] : 0;
        __syncthreads();
        ls[t] += xv;
        __syncthreads();
    }
    if (t < nch) chunk_sums[t] = (t == 0) ? 0 : ls[t - 1];  // exclusive
}

__global__ __launch_bounds__(256) void scanC_kernel(int* __restrict__ row_ptr,
                                                    const int* __restrict__ chunk_sums, int n) {
    const int base = blockIdx.x * CHUNK;
    const int off  = chunk_sums[blockIdx.x];
    for (int k = threadIdx.x; k < CHUNK; k += 256) {
        int i = base + k;
        if (i < n) row_ptr[i] += off;
    }
}

// ---------------- CSR build: deterministic counting partition ----------------

__global__ __launch_bounds__(256) void hist_kernel(const int* __restrict__ dst,
                                                   int* __restrict__ hist_g,
                                                   int e, int nbc, int nblk) {
    __shared__ int hs[512];
    const int t = threadIdx.x;
    for (int i = t; i < nbc; i += 256) hs[i] = 0;
    __syncthreads();
    const int e0  = blockIdx.x * EPB;
    const int lim = min(e0 + EPB, e);
    for (int i = e0 + t; i < lim; i += 256)
        atomicAdd(&hs[dst[i] >> CSHIFT], 1);
    __syncthreads();
    for (int b = t; b < nbc; b += 256)
        hist_g[b * nblk + blockIdx.x] = hs[b];
}

// pairs entries are PACKED 32-bit: (dst_local << 17) | src   (N=100000 < 2^17)
__global__ __launch_bounds__(256) void partition_kernel(const int* __restrict__ src,
                                                        const int* __restrict__ dst,
                                                        const int* __restrict__ hist_scan,
                                                        int* __restrict__ pairs,
                                                        int e, int nbc, int nblk) {
    __shared__ int  hs[512];
    __shared__ int  lscan[512];
    __shared__ int  lfill[512];
    __shared__ int  base_s[512];
    __shared__ int  ls[256];
    __shared__ int2 sp[EPB];   // 32 KB staging
    const int t = threadIdx.x;
    for (int i = t; i < nbc; i += 256) { hs[i] = 0; lfill[i] = 0; }
    __syncthreads();
    const int e0  = blockIdx.x * EPB;
    const int lim = min(e0 + EPB, e);
    for (int i = e0 + t; i < lim; i += 256)
        atomicAdd(&hs[dst[i] >> CSHIFT], 1);
    __syncthreads();
    int v0 = (2 * t     < nbc) ? hs[2 * t]     : 0;
    int v1 = (2 * t + 1 < nbc) ? hs[2 * t + 1] : 0;
    ls[t] = v0 + v1;
    __syncthreads();
    for (int off = 1; off < 256; off <<= 1) {
        int xv = (t >= off) ? ls[t - off] : 0;
        __syncthreads();
        ls[t] += xv;
        __syncthreads();
    }
    int excl = (t == 0) ? 0 : ls[t - 1];
    if (2 * t     < nbc) lscan[2 * t]     = excl;
    if (2 * t + 1 < nbc) lscan[2 * t + 1] = excl + v0;
    for (int b = t; b < nbc; b += 256) base_s[b] = hist_scan[b * nblk + blockIdx.x];
    __syncthreads();
    for (int i = e0 + t; i < lim; i += 256) {
        int d = dst[i];
        int b = d >> CSHIFT;
        int r = atomicAdd(&lfill[b], 1);
        sp[lscan[b] + r] = make_int2(src[i], d);
    }
    __syncthreads();
    const int cnt = lim - e0;
    for (int i = t; i < cnt; i += 256) {
        int2 pr = sp[i];
        int  b  = pr.y >> CSHIFT;
        pairs[base_s[b] + (i - lscan[b])] = pr.x | ((pr.y & 255) << 17);
    }
}

// One block per 256-node bucket: per-node count + scan in LDS, then write
// row_ptr, dinv, and place csr_src. No global atomics anywhere.
__global__ __launch_bounds__(256) void bucket_finalize_kernel(const int* __restrict__ pairs,
                                                              const int* __restrict__ hist_scan,
                                                              int* __restrict__ row_ptr,
                                                              float* __restrict__ dinv,
                                                              int* __restrict__ csr_src,
                                                              int n, int e, int nbc, int nblk) {
    __shared__ int cnt_s[256];
    __shared__ int fill[256];
    __shared__ int ls[256];
    const int b   = blockIdx.x;
    const int nb0 = b << CSHIFT;
    const int t   = threadIdx.x;
    const int r0  = hist_scan[b * nblk];                       // bucket start
    const int r1  = (b + 1 < nbc) ? hist_scan[(b + 1) * nblk] : e;
    cnt_s[t] = 0;
    __syncthreads();
    for (int i = r0 + t; i < r1; i += 256)
        atomicAdd(&cnt_s[pairs[i] >> 17], 1);
    __syncthreads();
    int c = cnt_s[t];
    ls[t] = c;
    __syncthreads();
    for (int off = 1; off < 256; off <<= 1) {
        int xv = (t >= off) ? ls[t - off] : 0;
        __syncthreads();
        ls[t] += xv;
        __syncthreads();
    }
    int excl = (t == 0) ? 0 : ls[t - 1];
    int node = nb0 + t;
    if (node < n) {
        row_ptr[node] = r0 + excl;
        dinv[node]    = rsqrtf((float)(c + 1));   // +1 self-loop
    }
    fill[t] = r0 + excl;
    __syncthreads();
    for (int i = r0 + t; i < r1; i += 256) {
        int pr = pairs[i];
        int p  = atomicAdd(&fill[pr >> 17], 1);
        csr_src[p] = pr & 0x1FFFF;
    }
    if (b == 0 && t == 0) row_ptr[n] = e;
}

// ---------------- dense transform via MFMA: HS(fp16) = dinv[row] * (relu?)(X) @ W ----------------
// R11/R12-proven. A[m=lane&15][k=quad*8+j]; C/D: col=lane&15, row=quad*4+reg.
// XT = float (layer 1) or _Float16 (layer 2, out1 stored fp16).

template <int M, bool RELU, typename XT>
__global__ __launch_bounds__(256) void gemm_mfma_kernel(const XT* __restrict__ X,
                                                        const float* __restrict__ W,
                                                        const float* __restrict__ dinv,
                                                        __half* __restrict__ H, int nrows) {
    constexpr int NC = M / 16;                 // col-tiles: 8 (M=128) / 4 (M=64)
    __shared__ __align__(16) _Float16 Wf[NC * 4 * 64 * 8];   // 32 KB / 16 KB

    const int tid = threadIdx.x;

    for (int f = tid; f < NC * 4 * 64; f += 256) {
        int c    = f >> 8;
        int i    = (f >> 6) & 3;
        int lane = f & 63;
        int quad = lane >> 4, n = lane & 15;
        const float* wp = W + (size_t)(i * 32 + quad * 8) * M + c * 16 + n;
        half8 hv;
#pragma unroll
        for (int j = 0; j < 8; ++j) hv[j] = (_Float16)wp[(size_t)j * M];
        ((half8*)Wf)[f] = hv;
    }
    __syncthreads();

    const int  wave = tid >> 6, lane = tid & 63;
    const int  quad = lane >> 4, n16 = lane & 15;
    const long rowbase = (long)blockIdx.x * 64 + wave * 16;

    long arow = rowbase + n16;
    const XT* xrow = X + (size_t)(arow < nrows ? arow : 0) * 128;
    half8 a[4];
    if constexpr (sizeof(XT) == 4) {   // fp32 input
        const float4* xr = (const float4*)xrow;
#pragma unroll
        for (int i = 0; i < 4; ++i) {
            float4 x0 = xr[i * 8 + quad * 2];
            float4 x1 = xr[i * 8 + quad * 2 + 1];
            if (RELU) {
                x0.x = fmaxf(x0.x, 0.f); x0.y = fmaxf(x0.y, 0.f);
                x0.z = fmaxf(x0.z, 0.f); x0.w = fmaxf(x0.w, 0.f);
                x1.x = fmaxf(x1.x, 0.f); x1.y = fmaxf(x1.y, 0.f);
                x1.z = fmaxf(x1.z, 0.f); x1.w = fmaxf(x1.w, 0.f);
            }
            half8 hv;
            hv[0] = (_Float16)x0.x; hv[1] = (_Float16)x0.y;
            hv[2] = (_Float16)x0.z; hv[3] = (_Float16)x0.w;
            hv[4] = (_Float16)x1.x; hv[5] = (_Float16)x1.y;
            hv[6] = (_Float16)x1.z; hv[7] = (_Float16)x1.w;
            a[i] = hv;
        }
    } else {                           // fp16 input (out1)
        const half8* xr = (const half8*)xrow;
#pragma unroll
        for (int i = 0; i < 4; ++i) {
            half8 hv = xr[i * 4 + quad];
            if (RELU) {
#pragma unroll
                for (int j = 0; j < 8; ++j)
                    hv[j] = (hv[j] > (_Float16)0) ? hv[j] : (_Float16)0;
            }
            a[i] = hv;
        }
    }

    float dv[4];
#pragma unroll
    for (int r = 0; r < 4; ++r) {
        long orow = rowbase + quad * 4 + r;
        dv[r] = (orow < nrows) ? dinv[orow] : 0.f;
    }

    for (int c = 0; c < NC; ++c) {
        f32x4 acc = {0.f, 0.f, 0.f, 0.f};
#pragma unroll
        for (int i = 0; i < 4; ++i) {
            half8 b = ((const half8*)Wf)[(c * 4 + i) * 64 + lane];
            acc = __builtin_amdgcn_mfma_f32_16x16x32_f16(a[i], b, acc, 0, 0, 0);
        }
#pragma unroll
        for (int r = 0; r < 4; ++r) {
            long orow = rowbase + quad * 4 + r;
            if (orow < nrows)
                H[orow * M + c * 16 + n16] = __float2half(acc[r] * dv[r]);
        }
    }
}

// ---------------- pull aggregation layer 1: out1(fp16) = b + dinv_d*(hs_d + sum hs_s) ----------------
// R12-proven 16/4/1 cascade; store fp16 (half2 per lane).

__global__ __launch_bounds__(TPB) void agg_pull128_kernel(const __half* __restrict__ hs,
                                                          const int* __restrict__ csr_src,
                                                          const int* __restrict__ row_ptr,
                                                          const float* __restrict__ dinv,
                                                          const float* __restrict__ bias,
                                                          __half* __restrict__ out, int n) {
    const int node = blockIdx.x * (TPB / 64) + (threadIdx.x >> 6);
    const int lane = threadIdx.x & 63;
    if (node >= n) return;
    const int beg = row_ptr[node];
    const int end = row_ptr[node + 1];

    const __half2* hp = (const __half2*)hs;
    float2 a[16];
#pragma unroll
    for (int r = 1; r < 16; ++r) a[r] = make_float2(0.f, 0.f);
    a[0] = __half22float2(hp[(long)node * 64 + lane]);  // self-loop term
    for (int base = beg; base < end; base += 64) {
        int m = end - base; if (m > 64) m = 64;
        int idx = (lane < m) ? csr_src[base + lane] : 0;
        int j = 0;
        for (; j + 16 <= m; j += 16) {
#pragma unroll
            for (int r = 0; r < 16; ++r) {
                int s = __shfl(idx, j + r);
                float2 v = __half22float2(hp[(long)s * 64 + lane]);
                a[r].x += v.x; a[r].y += v.y;
            }
        }
        for (; j + 4 <= m; j += 4) {
#pragma unroll
            for (int r = 0; r < 4; ++r) {
                int s = __shfl(idx, j + r);
                float2 v = __half22float2(hp[(long)s * 64 + lane]);
                a[r].x += v.x; a[r].y += v.y;
            }
        }
        for (; j < m; ++j) {
            int s = __shfl(idx, j);
            float2 v = __half22float2(hp[(long)s * 64 + lane]);
            a[0].x += v.x; a[0].y += v.y;
        }
    }
#pragma unroll
    for (int r = 8; r < 16; ++r) { a[r - 8].x += a[r].x; a[r - 8].y += a[r].y; }
#pragma unroll
    for (int r = 4; r < 8; ++r) { a[r - 4].x += a[r].x; a[r - 4].y += a[r].y; }
    float  di = dinv[node];
    float2 bv = ((const float2*)bias)[lane];
    float ox = bv.x + di * ((a[0].x + a[1].x) + (a[2].x + a[3].x));
    float oy = bv.y + di * ((a[0].y + a[1].y) + (a[2].y + a[3].y));
    ((__half2*)out)[(long)node * 64 + lane] = __floats2half2_rn(ox, oy);
}

// ---------------- pull aggregation layer 2: out(fp32) = b + dinv_d*(hs_d + sum hs_s) ----------------
// 2 edges per wave (32 lanes x half2 = one 128-B row each). Tail is
// divergence-safe: shfl + load execute on ALL lanes, accumulate predicated.

__global__ __launch_bounds__(TPB) void agg_pull64_kernel(const __half* __restrict__ hs,
                                                         const int* __restrict__ csr_src,
                                                         const int* __restrict__ row_ptr,
                                                         const float* __restrict__ dinv,
                                                         const float* __restrict__ bias,
                                                         float* __restrict__ out, int n) {
    const int node = blockIdx.x * (TPB / 64) + (threadIdx.x >> 6);
    const int lane = threadIdx.x & 63;
    if (node >= n) return;
    const int half = lane >> 5;   // which edge of the pair
    const int sl   = lane & 31;   // half2 column index within row
    const int beg = row_ptr[node];
    const int end = row_ptr[node + 1];
    const __half2* hp = (const __half2*)hs;

    float2 a[8];
#pragma unroll
    for (int r = 0; r < 8; ++r) a[r] = make_float2(0.f, 0.f);

    for (int base = beg; base < end; base += 64) {
        int m = end - base; if (m > 64) m = 64;
        int idx = (lane < m) ? csr_src[base + lane] : 0;
        int j = 0;
        for (; j + 16 <= m; j += 16) {
#pragma unroll
            for (int r = 0; r < 8; ++r) {
                int s = __shfl(idx, j + 2 * r + half);
                float2 v = __half22float2(hp[(long)s * 32 + sl]);
                a[r].x += v.x; a[r].y += v.y;
            }
        }
        for (; j + 2 <= m; j += 2) {
            int s = __shfl(idx, j + half);
            float2 v = __half22float2(hp[(long)s * 32 + sl]);
            a[0].x += v.x; a[0].y += v.y;
        }
        if (j < m) {  // single leftover edge; uniform branch, shfl by all lanes
            int s = __shfl(idx, j);
            float2 v = __half22float2(hp[(long)s * 32 + sl]);
            if (half == 0) { a[0].x += v.x; a[0].y += v.y; }
        }
    }
#pragma unroll
    for (int r = 4; r < 8; ++r) { a[r - 4].x += a[r].x; a[r - 4].y += a[r].y; }
    float2 acc;
    acc.x = (a[0].x + a[1].x) + (a[2].x + a[3].x);
    acc.y = (a[0].y + a[1].y) + (a[2].y + a[3].y);
    // combine the two halves (lanes l and l^32 hold the same columns)
    acc.x += __shfl(acc.x, lane ^ 32);
    acc.y += __shfl(acc.y, lane ^ 32);
    if (half == 0) {
        float2 sv = __half22float2(hp[(long)node * 32 + sl]);  // self-loop
        float  di = dinv[node];
        float2 bv = ((const float2*)bias)[sl];
        float2 o;
        o.x = bv.x + di * (acc.x + sv.x);
        o.y = bv.y + di * (acc.y + sv.y);
        ((float2*)out)[(long)node * 32 + sl] = o;
    }
}

// ---------------- launcher ----------------

extern "C" void kernel_launch(void* const* d_in, const int* in_sizes, int n_in,
                              void* d_out, int out_size, void* d_ws, size_t ws_size,
                              hipStream_t stream) {
    const float* x  = (const float*)d_in[0];
    const int*   ei = (const int*)d_in[1];   // int32 on the wire
    const float* W1 = (const float*)d_in[2];
    const float* b1 = (const float*)d_in[3];
    const float* W2 = (const float*)d_in[4];
    const float* b2 = (const float*)d_in[5];
    float* out = (float*)d_out;

    const int N = in_sizes[0] / 128;   // 100000
    const int E = in_sizes[1] / 2;     // 1600000
    const int* srcv = ei;
    const int* dstv = ei + E;

    const int NBC    = (N + 255) >> CSHIFT;           // 391 coarse buckets
    const int NBLK_E = (E + EPB - 1) / EPB;           // 391 edge blocks
    const int HLEN   = NBC * NBLK_E;                  // 152,881
    const int NCHH   = (HLEN + CHUNK - 1) / CHUNK;    // 150

    // workspace layout
    char* p = (char*)d_ws;
    int*    row_ptr    = (int*)p;           p += ((size_t)N + 64) * 4;
    int*    chunk_sums = (int*)p;           p += 1024;
    int*    hist       = (int*)p;           p += ((size_t)HLEN + 64) * 4;
    int*    csr_src    = (int*)p;           p += (size_t)E * 4;
    float*  dinv       = (float*)p;         p += ((size_t)N + 64) * 4;
    __half* hs1        = (__half*)p;        p += (size_t)N * 128 * 2;
    __half* out1       = (__half*)p;        p += (size_t)N * 128 * 2;
    int*    pairs      = (int*)out1;        // alias: out1 dead until after CSR build (E*4 <= N*256)
    __half* hs2        = hs1;               // hs1 dead once out1 complete

    // ---- CSR build + normalization (histogram -> scan -> partition -> finalize) ----
    hist_kernel<<<NBLK_E, 256, 0, stream>>>(dstv, hist, E, NBC, NBLK_E);
    scanA_kernel<<<NCHH, 256, 0, stream>>>(hist, hist, chunk_sums, HLEN);  // in-place safe
    scanB_kernel<<<1, 256, 0, stream>>>(chunk_sums, NCHH);
    scanC_kernel<<<NCHH, 256, 0, stream>>>(hist, chunk_sums, HLEN);
    partition_kernel<<<NBLK_E, 256, 0, stream>>>(srcv, dstv, hist, pairs, E, NBC, NBLK_E);
    bucket_finalize_kernel<<<NBC, 256, 0, stream>>>(pairs, hist, row_ptr, dinv, csr_src,
                                                    N, E, NBC, NBLK_E);

    // ---- layer 1: MFMA GEMM (fp32 in, fp16 out), agg -> fp16 out1 ----
    gemm_mfma_kernel<128, false, float><<<(N + 63) / 64, 256, 0, stream>>>(x, W1, dinv, hs1, N);
    agg_pull128_kernel<<<(N + 3) / 4, TPB, 0, stream>>>(hs1, csr_src, row_ptr, dinv, b1, out1, N);

    // ---- layer 2: MFMA GEMM (fp16 in w/ fused ReLU), agg -> fp32 d_out ----
    gemm_mfma_kernel<64, true, _Float16><<<(N + 63) / 64, 256, 0, stream>>>(
        (const _Float16*)out1, W2, dinv, hs2, N);
    agg_pull64_kernel<<<(N + 3) / 4, TPB, 0, stream>>>(hs2, csr_src, row_ptr, dinv, b2, out, N);
}